// Round 2
// baseline (453.924 us; speedup 1.0000x reference)
//
#include <hip/hip_runtime.h>
#include <hip/hip_bf16.h>

// HyperbolicGraphConstructor: fused Poincare-ball graph construction + propagation.
// R2: fused_kernel 4-way j-split (grid 256x4 -> 4 blocks/CU, 100% occupancy),
//     LDS diet (S2 tile removed; Q-merge in-place), P pre-scaled into nv2p,
//     raw v_exp/v_rcp tanh, uniform diag branch, atomicAdd partial combine.

typedef __attribute__((ext_vector_type(8))) short short8;
typedef __attribute__((ext_vector_type(4))) float f32x4;

#define MAXN 0.996f   /* (1 - 4e-3)/sqrt(c) */

__device__ __forceinline__ float artanh_clip(float x) {
    x = fminf(x, 1.0f - 1e-7f);
    x = fmaxf(x, -1.0f + 1e-7f);
    return 0.5f * logf((1.0f + x) / (1.0f - x));
}

__device__ __forceinline__ float red8(float v) {
    v += __shfl_xor(v, 1);
    v += __shfl_xor(v, 2);
    v += __shfl_xor(v, 4);
    return v;
}

__device__ __forceinline__ float red64(float v) {
#pragma unroll
    for (int m = 1; m < 64; m <<= 1) v += __shfl_xor(v, m);
    return v;
}

__device__ __forceinline__ unsigned short f2bf(float f) {
    __hip_bfloat16 h = __float2bfloat16(f);
    return *reinterpret_cast<unsigned short*>(&h);
}

__device__ __forceinline__ float bf2f(unsigned short u) {
    __hip_bfloat16 h;
    *reinterpret_cast<unsigned short*>(&h) = u;
    return __bfloat162float(h);
}

// ---------------------------------------------------------------- hb --------
__global__ void hb_kernel(const float* __restrict__ b1, const float* __restrict__ b2,
                          float* __restrict__ hbws) {
    const int l = threadIdx.x;  // 64 threads
    for (int which = 0; which < 2; ++which) {
        const float* b = which ? b2 : b1;
        float e0 = b[l], e1 = b[l + 64];
        float n = fmaxf(sqrtf(red64(e0 * e0 + e1 * e1)), 1e-15f);
        float th = tanhf(n);
        float s0 = th / n;
        float u0 = e0 * s0, u1 = e1 * s0;
        float nu = fmaxf(sqrtf(red64(u0 * u0 + u1 * u1)), 1e-15f);
        float ps = (nu > MAXN) ? MAXN / nu : 1.0f;
        float h0 = u0 * ps, h1 = u1 * ps;
        float y2 = red64(h0 * h0 + h1 * h1);
        hbws[which * 128 + l] = h0;
        hbws[which * 128 + l + 64] = h1;
        if (l == 0) hbws[256 + which] = y2;
    }
}

// ---------------------------------------------------------------- prep ------
// grid (256, 2), block 256: 32 rows/block; which=0 -> nv1, which=1 -> nv2
__global__ __launch_bounds__(256) void prep_kernel(
    const int* __restrict__ idx,
    const float* __restrict__ emb1, const float* __restrict__ emb2,
    const float* __restrict__ W1, const float* __restrict__ W2,
    const float* __restrict__ hbws,
    unsigned short* __restrict__ nv1b, unsigned short* __restrict__ nv2b,
    float* __restrict__ xn1, float* __restrict__ xn2) {
    __shared__ __align__(16) float uL[32 * 132];
    __shared__ float mxL[32 * 132];
    __shared__ float xnL[32];
    __shared__ float hbL[128];

    const int which = blockIdx.y;
    const float* emb = which ? emb2 : emb1;
    const float* W = which ? W2 : W1;
    unsigned short* nvb = which ? nv2b : nv1b;
    float* xno = which ? xn2 : xn1;
    const float y2 = hbws[256 + which];

    const int tid = threadIdx.x;
    const int rblk = blockIdx.x * 32;
    if (tid < 128) hbL[tid] = hbws[which * 128 + tid];

    // phase A: expmap0 + proj per row; 8 threads/row, 16 elems/thread
    const int r = tid >> 3, s = tid & 7;
    const int row = rblk + r;
    const int src = idx[row];
    float ev[16];
    float p2 = 0.f;
#pragma unroll
    for (int kk = 0; kk < 16; ++kk) {
        float e = emb[src * 128 + s + kk * 8];
        ev[kk] = e;
        p2 += e * e;
    }
    float n2 = red8(p2);
    float n = fmaxf(sqrtf(n2), 1e-15f);
    float th = tanhf(n);
    float nu = fmaxf(th, 1e-15f);               // ||expmap0(e)||
    float ps = (nu > MAXN) ? (MAXN / nu) : 1.0f;
    float sc0 = (th / n) * ps;
#pragma unroll
    for (int kk = 0; kk < 16; ++kk) uL[r * 132 + s + kk * 8] = ev[kk] * sc0;
    if (s == 0) xnL[r] = fmaxf(nu * ps, 1e-15f);
    __syncthreads();

    // phase B: mx = u @ W^T  (thread: output col o, rows rb, rb+2, ...)
    const int o = tid & 127, rb = tid >> 7;
    float mxv[16];
#pragma unroll
    for (int rr = 0; rr < 16; ++rr) mxv[rr] = 0.f;
    for (int k4 = 0; k4 < 128; k4 += 4) {
        const float4 wv = *reinterpret_cast<const float4*>(&W[o * 128 + k4]);
#pragma unroll
        for (int rr = 0; rr < 16; ++rr) {
            const float4 uv = *reinterpret_cast<const float4*>(&uL[(rb + rr * 2) * 132 + k4]);
            mxv[rr] += uv.x * wv.x + uv.y * wv.y + uv.z * wv.z + uv.w * wv.w;
        }
    }
#pragma unroll
    for (int rr = 0; rr < 16; ++rr) mxL[(rb + rr * 2) * 132 + o] = mxv[rr];
    __syncthreads();

    // phase C: mobius_matvec scale + proj + mobius_add(hb) + proj
    float mx[16];
    float m2 = 0.f;
#pragma unroll
    for (int kk = 0; kk < 16; ++kk) {
        mx[kk] = mxL[r * 132 + s + kk * 8];
        m2 += mx[kk] * mx[kk];
    }
    float mxn = fmaxf(sqrtf(red8(m2)), 1e-15f);
    float xnv = xnL[r];
    float tt = tanhf(mxn / xnv * artanh_clip(xnv));
    float nres = fmaxf(tt, 1e-15f);             // ||res||
    float ps2 = (nres > MAXN) ? (MAXN / nres) : 1.0f;
    float s2 = (tt / mxn) * ps2;                // mv = mx * s2
    float mvn = nres * ps2;
    float x2 = mvn * mvn;
    float xyp = 0.f;
    float mv[16];
#pragma unroll
    for (int kk = 0; kk < 16; ++kk) {
        mv[kk] = mx[kk] * s2;
        xyp += mv[kk] * hbL[s + kk * 8];
    }
    float xy = red8(xyp);
    float cA = 1.f + 2.f * xy + y2;
    float cB = 1.f - x2;
    float rden = 1.f / fmaxf(1.f + 2.f * xy + x2 * y2, 1e-15f);
    float r2v[16];
    float q2 = 0.f;
#pragma unroll
    for (int kk = 0; kk < 16; ++kk) {
        float v = (cA * mv[kk] + cB * hbL[s + kk * 8]) * rden;
        r2v[kk] = v;
        q2 += v * v;
    }
    float nr2 = fmaxf(sqrtf(red8(q2)), 1e-15f);
    float ps3 = (nr2 > MAXN) ? (MAXN / nr2) : 1.0f;
#pragma unroll
    for (int kk = 0; kk < 16; ++kk) nvb[row * 128 + s + kk * 8] = f2bf(r2v[kk] * ps3);
    if (s == 0) xno[row] = fmaxf((nr2 > MAXN) ? MAXN : nr2, 1e-15f);
}

// ---------------------------------------------------------------- xt --------
// grid 256, block 256: 32 rows/block; writes xt transposed [128][8192] bf16
__global__ __launch_bounds__(256) void xt_kernel(const float* __restrict__ x,
                                                 unsigned short* __restrict__ xtT) {
    __shared__ float xv[32 * 132];
    const int tid = threadIdx.x;
    const int rblk = blockIdx.x * 32;
    const int r = tid >> 3, s = tid & 7;
    float ev[16];
    float p2 = 0.f;
#pragma unroll
    for (int kk = 0; kk < 16; ++kk) {
        float e = x[(rblk + r) * 128 + s + kk * 8];
        ev[kk] = e;
        p2 += e * e;
    }
    const float n = fmaxf(sqrtf(red8(p2)), 1e-15f);
    const float scl = artanh_clip(n) / n;
#pragma unroll
    for (int kk = 0; kk < 16; ++kk) xv[r * 132 + s + kk * 8] = ev[kk] * scl;
    __syncthreads();
    const int k = tid >> 1, h = tid & 1;
    short8 o0, o1;
#pragma unroll
    for (int j = 0; j < 8; ++j) o0[j] = (short)f2bf(xv[(h * 16 + j) * 132 + k]);
#pragma unroll
    for (int j = 0; j < 8; ++j) o1[j] = (short)f2bf(xv[(h * 16 + 8 + j) * 132 + k]);
    *reinterpret_cast<short8*>(&xtT[k * 8192 + rblk + h * 16]) = o0;
    *reinterpret_cast<short8*>(&xtT[k * 8192 + rblk + h * 16 + 8]) = o1;
}

// ---------------------------------------------------------------- gram ------
// grid (16, 3, 8), block 256. mat: 0->G1(nv1,nv1) 1->G2(nv2,nv2) 2->M(nv1,nv2)
__global__ __launch_bounds__(256) void gram_kernel(const unsigned short* __restrict__ nv1b,
                                                   const unsigned short* __restrict__ nv2b,
                                                   float* __restrict__ G) {
    __shared__ float Ab[64 * 33], Bb[64 * 33];
    const int tile = blockIdx.x, mat = blockIdx.y, kc = blockIdx.z;
    const int ta = (tile & 3) * 32, tb = (tile >> 2) * 32;
    const unsigned short* Am = (mat == 1) ? nv2b : nv1b;
    const unsigned short* Bm = (mat == 0) ? nv1b : nv2b;
    const int tid = threadIdx.x;
    const int oa = tid & 31, obb = (tid >> 5) * 4;
    float acc[4] = {0.f, 0.f, 0.f, 0.f};
    for (int sc = 0; sc < 16; ++sc) {
        const int r0 = kc * 1024 + sc * 64;
        for (int i0 = tid; i0 < 2048; i0 += 256) {
            int rr = i0 >> 5, cc = i0 & 31;
            Ab[rr * 33 + cc] = bf2f(Am[(r0 + rr) * 128 + ta + cc]);
            Bb[rr * 33 + cc] = bf2f(Bm[(r0 + rr) * 128 + tb + cc]);
        }
        __syncthreads();
#pragma unroll 4
        for (int rr = 0; rr < 64; ++rr) {
            float av = Ab[rr * 33 + oa];
#pragma unroll
            for (int i = 0; i < 4; ++i) acc[i] += av * Bb[rr * 33 + obb + i];
        }
        __syncthreads();
    }
#pragma unroll
    for (int i = 0; i < 4; ++i)
        atomicAdd(&G[mat * 16384 + (ta + oa) * 128 + tb + obb + i], acc[i]);
}

// ---------------------------------------------------------------- rowcoef ---
// grid 256, block 256: 32 rows/block. R=v2'G1v2, C=v1'G2v1, X=v2'Mv1 -> P,Q
// Also writes nv2p = bf16(P_i * nv2_i) for the fused kernel's prescaled S GEMM.
__global__ __launch_bounds__(256) void rowcoef_kernel(
    const float* __restrict__ G, const float* __restrict__ xn1, const float* __restrict__ xn2,
    const unsigned short* __restrict__ nv1b, const unsigned short* __restrict__ nv2b,
    float* __restrict__ P, float* __restrict__ Q, unsigned short* __restrict__ nv2p) {
    __shared__ __align__(16) float v1L[32 * 132];
    __shared__ __align__(16) float v2L[32 * 132];
    __shared__ float tL[32 * 132];
    __shared__ float RCX[3][32];
    __shared__ float PshL[32];
    const int tid = threadIdx.x;
    const int rblk = blockIdx.x * 32;
    for (int i = tid; i < 4096; i += 256) {
        int r = i >> 7, c = i & 127;
        v1L[r * 132 + c] = bf2f(nv1b[(rblk + r) * 128 + c]);
        v2L[r * 132 + c] = bf2f(nv2b[(rblk + r) * 128 + c]);
    }
    __syncthreads();
    const int o = tid & 127, rb = tid >> 7;
    const int rA = tid >> 3, sA = tid & 7;
    for (int mat = 0; mat < 3; ++mat) {
        const float* vR = (mat == 0) ? v2L : v1L;      // w = G * vR
        const float* vL = (mat == 1) ? v1L : v2L;      // form = <vL, w>
        const float* Gm = G + mat * 16384;
        float tv[16];
#pragma unroll
        for (int rr = 0; rr < 16; ++rr) tv[rr] = 0.f;
        for (int k4 = 0; k4 < 128; k4 += 4) {
            const float4 gv = *reinterpret_cast<const float4*>(&Gm[o * 128 + k4]);
#pragma unroll
            for (int rr = 0; rr < 16; ++rr) {
                const float4 uv = *reinterpret_cast<const float4*>(&vR[(rb + rr * 2) * 132 + k4]);
                tv[rr] += uv.x * gv.x + uv.y * gv.y + uv.z * gv.z + uv.w * gv.w;
            }
        }
        __syncthreads();  // previous-mat tL consumers done
#pragma unroll
        for (int rr = 0; rr < 16; ++rr) {
            int rw = rb + rr * 2;
            tL[rw * 132 + o] = vL[rw * 132 + o] * tv[rr];
        }
        __syncthreads();
        float p = 0.f;
#pragma unroll
        for (int kk = 0; kk < 16; ++kk) p += tL[rA * 132 + sA + kk * 8];
        p = red8(p);
        if (sA == 0) RCX[mat][rA] = p;
    }
    __syncthreads();
    if (tid < 32) {
        const int row = rblk + tid;
        const float R = RCX[0][tid], Cc = RCX[1][tid], X = RCX[2][tid];
        const float xn1v = xn1[row], xn2v = xn2[row];
        const float mxn1 = fmaxf(sqrtf(fmaxf(R, 0.f)), 1e-15f);
        const float t1 = tanhf(mxn1 / xn2v * artanh_clip(xn2v));
        const float f1 = t1 / mxn1;
        const float mxn2 = fmaxf(sqrtf(fmaxf(Cc, 0.f)), 1e-15f);
        const float t2 = tanhf(mxn2 / xn1v * artanh_clip(xn1v));
        const float f2 = t2 / mxn2;
        const float x2 = f1 * f1 * R, y2 = f2 * f2 * Cc;
        const float xy = -f1 * f2 * X;
        const float rden = 1.f / fmaxf(1.f + 2.f * xy + x2 * y2, 1e-15f);
        const float Pv = (1.f + 2.f * xy + y2) * f1 * rden;
        P[row] = Pv;
        PshL[tid] = Pv;
        Q[row] = -(1.f - x2) * f2 * rden;
    }
    __syncthreads();
    for (int i = tid; i < 4096; i += 256) {
        int r = i >> 7, c = i & 127;
        nv2p[(rblk + r) * 128 + c] = f2bf(PshL[r] * v2L[r * 132 + c]);
    }
}

// ---------------------------------------------------------------- fused -----
// grid (256, 4), block 512 (8 waves): 32 output rows/block, 16 j-steps of 128.
// Partial U/rs/qs combined across the 4 j-splits via atomicAdd (buffers zeroed
// at launch). a[i][j] = (P_i nv2_i)·nv1_j  (+ Q_i S2 in-place merge if needed).
__global__ __launch_bounds__(512, 8) void fused_kernel(
    const unsigned short* __restrict__ nv1b, const unsigned short* __restrict__ nv2p,
    const unsigned short* __restrict__ nv2b, const unsigned short* __restrict__ xtT,
    const float* __restrict__ Q,
    float* __restrict__ U, float* __restrict__ rs, float* __restrict__ qs) {
    __shared__ float S1[32 * 132];                       // a[i, jblk + 0..127]
    __shared__ __align__(16) unsigned short adjb[32 * 136];
    __shared__ float QL[32];
    __shared__ int s2flag;

    const int tid = threadIdx.x;
    const int w = tid >> 6, l = tid & 63;
    const int iblk = blockIdx.x * 32;
    const int jb0 = blockIdx.y * 16;

    if (tid == 0) s2flag = 0;
    if (tid < 32) QL[tid] = Q[iblk + tid];
    __syncthreads();
    if (tid < 32 && fabsf(QL[tid]) > 1e-6f) atomicOr(&s2flag, 1);
    __syncthreads();
    const bool needS2 = (s2flag != 0);

    // persistent A fragments: P-prescaled nv2 rows iblk..iblk+31, full K=128
    short8 areg[2][4];
#pragma unroll
    for (int tr = 0; tr < 2; ++tr)
#pragma unroll
        for (int kk = 0; kk < 4; ++kk)
            areg[tr][kk] = *reinterpret_cast<const short8*>(
                &nv2p[(iblk + tr * 16 + (l & 15)) * 128 + kk * 32 + (l >> 4) * 8]);

    const f32x4 zero4 = {0.f, 0.f, 0.f, 0.f};
    f32x4 accU[2];
    accU[0] = zero4;
    accU[1] = zero4;
    float rsA[4] = {0.f, 0.f, 0.f, 0.f};
    float qA[4] = {0.f, 0.f, 0.f, 0.f};

    auto computeS1 = [&](int jb) {
        const int jblk = jb * 128;
        f32x4 acc0 = zero4, acc1 = zero4;
#pragma unroll
        for (int kk = 0; kk < 4; ++kk) {
            short8 b = *reinterpret_cast<const short8*>(
                &nv1b[(jblk + w * 16 + (l & 15)) * 128 + kk * 32 + (l >> 4) * 8]);
            acc0 = __builtin_amdgcn_mfma_f32_16x16x32_bf16(areg[0][kk], b, acc0, 0, 0, 0);
            acc1 = __builtin_amdgcn_mfma_f32_16x16x32_bf16(areg[1][kk], b, acc1, 0, 0, 0);
        }
#pragma unroll
        for (int v = 0; v < 4; ++v) {
            S1[((l >> 4) * 4 + v) * 132 + w * 16 + (l & 15)] = acc0[v];
            S1[(16 + (l >> 4) * 4 + v) * 132 + w * 16 + (l & 15)] = acc1[v];
        }
    };

    // rare exact path: S1[i][j] += Q_i * (nv2_j . nv1_i), in place (barriered)
    auto s2merge = [&](int jb) {
        const int jblk = jb * 128;
        f32x4 a20 = zero4, a21 = zero4;
#pragma unroll
        for (int kk = 0; kk < 4; ++kk) {
            short8 a2 = *reinterpret_cast<const short8*>(
                &nv2b[(jblk + w * 16 + (l & 15)) * 128 + kk * 32 + (l >> 4) * 8]);
            short8 b20 = *reinterpret_cast<const short8*>(
                &nv1b[(iblk + (l & 15)) * 128 + kk * 32 + (l >> 4) * 8]);
            short8 b21 = *reinterpret_cast<const short8*>(
                &nv1b[(iblk + 16 + (l & 15)) * 128 + kk * 32 + (l >> 4) * 8]);
            a20 = __builtin_amdgcn_mfma_f32_16x16x32_bf16(a2, b20, a20, 0, 0, 0);
            a21 = __builtin_amdgcn_mfma_f32_16x16x32_bf16(a2, b21, a21, 0, 0, 0);
        }
        const int jloc = w * 16 + (l >> 4) * 4;
        const int i0 = l & 15;
#pragma unroll
        for (int v = 0; v < 4; ++v) {
            S1[i0 * 132 + jloc + v] += QL[i0] * a20[v];
            S1[(i0 + 16) * 132 + jloc + v] += QL[i0 + 16] * a21[v];
        }
    };

    computeS1(jb0);
    for (int jb = jb0; jb < jb0 + 16; ++jb) {
        const int jblk = jb * 128;
        __syncthreads();  // S1 ready; adjb free
        if (needS2) {
            s2merge(jb);
            __syncthreads();
        }
        // adj phase: rows w+8k, cols l and l+64. tanh(3a)=1-2/(exp2(8.656*a)+1)
        auto adjLoop = [&](bool dodiag) {
#pragma unroll
            for (int k = 0; k < 4; ++k) {
                const int r = w + 8 * k;
#pragma unroll
                for (int h = 0; h < 2; ++h) {
                    const int c = l + 64 * h;
                    float a = S1[r * 132 + c];
                    float e = __builtin_amdgcn_exp2f(a * 8.65617025f);
                    float t = 1.0f - 2.0f * __builtin_amdgcn_rcpf(e + 1.0f);
                    float ad = fmaxf(t, 0.0f);
                    if (dodiag && (iblk + r == jblk + c)) ad += 1e-4f;
                    rsA[k] += ad;
                    qA[k] += ad * ad;
                    adjb[r * 136 + c] = f2bf(ad);
                }
            }
        };
        if ((unsigned)(iblk - jblk) < 128u) adjLoop(true); else adjLoop(false);
        __syncthreads();  // adjb ready; S1 free
        // U += adjb[32][128] @ xt[jblk..][128cols]; wave w owns U cols w*16..+15
#pragma unroll
        for (int kk = 0; kk < 4; ++kk) {
            short8 b = *reinterpret_cast<const short8*>(
                &xtT[(w * 16 + (l & 15)) * 8192 + jblk + kk * 32 + (l >> 4) * 8]);
#pragma unroll
            for (int tr = 0; tr < 2; ++tr) {
                short8 a = *reinterpret_cast<const short8*>(
                    &adjb[(tr * 16 + (l & 15)) * 136 + kk * 32 + (l >> 4) * 8]);
                accU[tr] = __builtin_amdgcn_mfma_f32_16x16x32_bf16(a, b, accU[tr], 0, 0, 0);
            }
        }
        if (jb + 1 < jb0 + 16) computeS1(jb + 1);  // writes S1 post-bar2, read post-next-bar1
    }

    // combine partials (C layout: row=(l>>4)*4+v, col=l&15)
#pragma unroll
    for (int tr = 0; tr < 2; ++tr)
#pragma unroll
        for (int v = 0; v < 4; ++v)
            atomicAdd(&U[(iblk + tr * 16 + (l >> 4) * 4 + v) * 128 + w * 16 + (l & 15)],
                      accU[tr][v]);
#pragma unroll
    for (int k = 0; k < 4; ++k) {
        float rsv = red64(rsA[k]);
        float qv = red64(qA[k]);
        if (l == 0) {
            atomicAdd(&rs[iblk + w + 8 * k], rsv);
            atomicAdd(&qs[iblk + w + 8 * k], qv);
        }
    }
}

// ---------------------------------------------------------------- finalize --
__global__ void finalize_kernel(const float* __restrict__ U, const float* __restrict__ rs,
                                const float* __restrict__ qs, float* __restrict__ out) {
    const int row = blockIdx.x, l = threadIdx.x;  // 64 threads
    const float u0 = U[row * 128 + l], u1 = U[row * 128 + 64 + l];
    const float rsv = rs[row];
    const float wv = (rsv == 0.f) ? 0.f : 1.f / rsv;
    const float m0 = u0 * wv, m1 = u1 * wv;
    const float mxn = fmaxf(sqrtf(red64(m0 * m0 + m1 * m1)), 1e-15f);
    const float xn = fmaxf(sqrtf(fmaxf(qs[row], 0.f)) * wv, 1e-15f);
    const float tt = tanhf(mxn / xn * artanh_clip(xn));
    const float nres = fmaxf(tt, 1e-15f);
    const float lsc = (tt / mxn) * (artanh_clip(nres) / nres);
    out[row * 128 + l] = m0 * lsc;
    out[row * 128 + 64 + l] = m1 * lsc;
}

// ---------------------------------------------------------------- launch ----
extern "C" void kernel_launch(void* const* d_in, const int* in_sizes, int n_in,
                              void* d_out, int out_size, void* d_ws, size_t ws_size,
                              hipStream_t stream) {
    const int* idx = (const int*)d_in[0];
    const float* x = (const float*)d_in[2];
    const float* emb1 = (const float*)d_in[3];
    const float* emb2 = (const float*)d_in[4];
    const float* W1 = (const float*)d_in[5];
    const float* b1 = (const float*)d_in[6];
    const float* W2 = (const float*)d_in[7];
    const float* b2 = (const float*)d_in[8];
    float* out = (float*)d_out;
    char* ws = (char*)d_ws;

    unsigned short* nv1b = (unsigned short*)(ws + 0x000000);  // 2MB bf16 [8192][128]
    unsigned short* nv2b = (unsigned short*)(ws + 0x200000);  // 2MB
    unsigned short* xtT = (unsigned short*)(ws + 0x400000);   // 2MB bf16 [128][8192]
    unsigned short* nv2p = (unsigned short*)(ws + 0x600000);  // 2MB bf16 P-scaled nv2
    float* G = (float*)(ws + 0x800000);                       // 3 x 128x128 fp32
    float* hbws = (float*)(ws + 0x830000);                    // hb1,hb2,y2[2]
    float* xn1 = (float*)(ws + 0x831000);
    float* xn2 = (float*)(ws + 0x839000);
    float* P = (float*)(ws + 0x841000);
    float* Q = (float*)(ws + 0x849000);
    float* rs = (float*)(ws + 0x851000);
    float* qs = (float*)(ws + 0x859000);
    float* U = out;  // U accumulated (atomics) directly in d_out; finalize is row-local in-place

    hipMemsetAsync(G, 0, 3 * 128 * 128 * sizeof(float), stream);
    hipMemsetAsync(rs, 0, 8192 * sizeof(float), stream);
    hipMemsetAsync(qs, 0, 8192 * sizeof(float), stream);
    hipMemsetAsync(U, 0, 8192 * 128 * sizeof(float), stream);
    hb_kernel<<<1, 64, 0, stream>>>(b1, b2, hbws);
    prep_kernel<<<dim3(256, 2), 256, 0, stream>>>(idx, emb1, emb2, W1, W2, hbws,
                                                  nv1b, nv2b, xn1, xn2);
    xt_kernel<<<256, 256, 0, stream>>>(x, xtT);
    gram_kernel<<<dim3(16, 3, 8), 256, 0, stream>>>(nv1b, nv2b, G);
    rowcoef_kernel<<<256, 256, 0, stream>>>(G, xn1, xn2, nv1b, nv2b, P, Q, nv2p);
    fused_kernel<<<dim3(256, 4), 512, 0, stream>>>(nv1b, nv2p, nv2b, xtT, Q, U, rs, qs);
    finalize_kernel<<<8192, 64, 0, stream>>>(U, rs, qs, out);
    (void)in_sizes; (void)n_in; (void)out_size; (void)ws_size; (void)d_in;
}

// Round 4
// 344.839 us; speedup vs baseline: 1.3163x; 1.3163x over previous
//
#include <hip/hip_runtime.h>
#include <hip/hip_bf16.h>

// HyperbolicGraphConstructor R4:
//  - ws footprint shrunk to 6.6MB (R3's 25.7MB overflowed ws_size -> OOB writes
//    corrupted harness state; post-timing divergence). No Upart/nv2p buffers.
//  - fused: XCD-aware (iblk, j-quarter) mapping kept; partials combined via
//    atomicAdd into U=d_out (R2-proven); P applied in fp32 during adj phase.
//  - s2s shared-mem OOB write fixed.

typedef __attribute__((ext_vector_type(8))) short short8;
typedef __attribute__((ext_vector_type(4))) float f32x4;

#define MAXN 0.996f   /* (1 - 4e-3)/sqrt(c) */

__device__ __forceinline__ float artanh_clip(float x) {
    x = fminf(x, 1.0f - 1e-7f);
    x = fmaxf(x, -1.0f + 1e-7f);
    return 0.5f * logf((1.0f + x) / (1.0f - x));
}

__device__ __forceinline__ float red8(float v) {
    v += __shfl_xor(v, 1);
    v += __shfl_xor(v, 2);
    v += __shfl_xor(v, 4);
    return v;
}

__device__ __forceinline__ float red64(float v) {
#pragma unroll
    for (int m = 1; m < 64; m <<= 1) v += __shfl_xor(v, m);
    return v;
}

__device__ __forceinline__ unsigned short f2bf(float f) {
    __hip_bfloat16 h = __float2bfloat16(f);
    return *reinterpret_cast<unsigned short*>(&h);
}

__device__ __forceinline__ float bf2f(unsigned short u) {
    __hip_bfloat16 h;
    *reinterpret_cast<unsigned short*>(&h) = u;
    return __bfloat162float(h);
}

// ---------------------------------------------------------------- prep ------
// grid (256, 3), block 256: y=0 -> nv1 (emb1,W1,b1); y=1 -> nv2; y=2 -> xt.
__global__ __launch_bounds__(256) void prep_kernel(
    const int* __restrict__ idx, const float* __restrict__ x,
    const float* __restrict__ emb1, const float* __restrict__ emb2,
    const float* __restrict__ W1, const float* __restrict__ W2,
    const float* __restrict__ b1, const float* __restrict__ b2,
    unsigned short* __restrict__ nv1b, unsigned short* __restrict__ nv2b,
    unsigned short* __restrict__ xtT,
    float* __restrict__ xn1, float* __restrict__ xn2) {
    const int which = blockIdx.y;
    const int tid = threadIdx.x;
    const int rblk = blockIdx.x * 32;

    if (which == 2) {
        // ---- xt path: xt = logmap0(x), stored transposed [128][8192] bf16
        __shared__ float xv[32 * 132];
        const int r = tid >> 3, s = tid & 7;
        float ev[16];
        float p2 = 0.f;
#pragma unroll
        for (int kk = 0; kk < 16; ++kk) {
            float e = x[(rblk + r) * 128 + s + kk * 8];
            ev[kk] = e;
            p2 += e * e;
        }
        const float n = fmaxf(sqrtf(red8(p2)), 1e-15f);
        const float scl = artanh_clip(n) / n;
#pragma unroll
        for (int kk = 0; kk < 16; ++kk) xv[r * 132 + s + kk * 8] = ev[kk] * scl;
        __syncthreads();
        const int k = tid >> 1, h = tid & 1;
        short8 o0, o1;
#pragma unroll
        for (int j = 0; j < 8; ++j) o0[j] = (short)f2bf(xv[(h * 16 + j) * 132 + k]);
#pragma unroll
        for (int j = 0; j < 8; ++j) o1[j] = (short)f2bf(xv[(h * 16 + 8 + j) * 132 + k]);
        *reinterpret_cast<short8*>(&xtT[k * 8192 + rblk + h * 16]) = o0;
        *reinterpret_cast<short8*>(&xtT[k * 8192 + rblk + h * 16 + 8]) = o1;
        return;
    }

    __shared__ __align__(16) float uL[32 * 132];
    __shared__ float mxL[32 * 132];
    __shared__ float xnL[32];
    __shared__ float hbL[128];
    __shared__ float s2s[4];

    const float* emb = which ? emb2 : emb1;
    const float* W = which ? W2 : W1;
    const float* b = which ? b2 : b1;
    unsigned short* nvb = which ? nv2b : nv1b;
    float* xno = which ? xn2 : xn1;

    // ---- inline hb = proj(expmap0(b)); y2 = ||hb||^2 (= min(tanh||b||, MAXN)^2)
    float bv = (tid < 128) ? b[tid] : 0.f;
    float ssq = red64(bv * bv);
    if ((tid & 63) == 0) s2s[tid >> 6] = ssq;  // waves 2,3 write zeros (in-bounds)
    __syncthreads();
    const float bn = fmaxf(sqrtf(s2s[0] + s2s[1]), 1e-15f);
    const float bth = tanhf(bn);
    const float bnu = fmaxf(bth, 1e-15f);
    const float bps = (bnu > MAXN) ? (MAXN / bnu) : 1.0f;
    if (tid < 128) hbL[tid] = bv * (bth / bn) * bps;
    const float hbn = fminf(bnu, MAXN);
    const float y2 = hbn * hbn;

    // phase A: expmap0 + proj per row; 8 threads/row, 16 elems/thread
    const int r = tid >> 3, s = tid & 7;
    const int row = rblk + r;
    const int src = idx[row];
    float ev[16];
    float p2 = 0.f;
#pragma unroll
    for (int kk = 0; kk < 16; ++kk) {
        float e = emb[src * 128 + s + kk * 8];
        ev[kk] = e;
        p2 += e * e;
    }
    float n2 = red8(p2);
    float n = fmaxf(sqrtf(n2), 1e-15f);
    float th = tanhf(n);
    float nu = fmaxf(th, 1e-15f);               // ||expmap0(e)||
    float ps = (nu > MAXN) ? (MAXN / nu) : 1.0f;
    float sc0 = (th / n) * ps;
#pragma unroll
    for (int kk = 0; kk < 16; ++kk) uL[r * 132 + s + kk * 8] = ev[kk] * sc0;
    if (s == 0) xnL[r] = fmaxf(nu * ps, 1e-15f);
    __syncthreads();

    // phase B: mx = u @ W^T  (thread: output col o, rows rb, rb+2, ...)
    const int o = tid & 127, rb = tid >> 7;
    float mxv[16];
#pragma unroll
    for (int rr = 0; rr < 16; ++rr) mxv[rr] = 0.f;
    for (int k4 = 0; k4 < 128; k4 += 4) {
        const float4 wv = *reinterpret_cast<const float4*>(&W[o * 128 + k4]);
#pragma unroll
        for (int rr = 0; rr < 16; ++rr) {
            const float4 uv = *reinterpret_cast<const float4*>(&uL[(rb + rr * 2) * 132 + k4]);
            mxv[rr] += uv.x * wv.x + uv.y * wv.y + uv.z * wv.z + uv.w * wv.w;
        }
    }
#pragma unroll
    for (int rr = 0; rr < 16; ++rr) mxL[(rb + rr * 2) * 132 + o] = mxv[rr];
    __syncthreads();

    // phase C: mobius_matvec scale + proj + mobius_add(hb) + proj
    float mx[16];
    float m2 = 0.f;
#pragma unroll
    for (int kk = 0; kk < 16; ++kk) {
        mx[kk] = mxL[r * 132 + s + kk * 8];
        m2 += mx[kk] * mx[kk];
    }
    float mxn = fmaxf(sqrtf(red8(m2)), 1e-15f);
    float xnv = xnL[r];
    float tt = tanhf(mxn / xnv * artanh_clip(xnv));
    float nres = fmaxf(tt, 1e-15f);             // ||res||
    float ps2 = (nres > MAXN) ? (MAXN / nres) : 1.0f;
    float s2 = (tt / mxn) * ps2;                // mv = mx * s2
    float mvn = nres * ps2;
    float x2 = mvn * mvn;
    float xyp = 0.f;
    float mv[16];
#pragma unroll
    for (int kk = 0; kk < 16; ++kk) {
        mv[kk] = mx[kk] * s2;
        xyp += mv[kk] * hbL[s + kk * 8];
    }
    float xy = red8(xyp);
    float cA = 1.f + 2.f * xy + y2;
    float cB = 1.f - x2;
    float rden = 1.f / fmaxf(1.f + 2.f * xy + x2 * y2, 1e-15f);
    float r2v[16];
    float q2 = 0.f;
#pragma unroll
    for (int kk = 0; kk < 16; ++kk) {
        float v = (cA * mv[kk] + cB * hbL[s + kk * 8]) * rden;
        r2v[kk] = v;
        q2 += v * v;
    }
    float nr2 = fmaxf(sqrtf(red8(q2)), 1e-15f);
    float ps3 = (nr2 > MAXN) ? (MAXN / nr2) : 1.0f;
#pragma unroll
    for (int kk = 0; kk < 16; ++kk) nvb[row * 128 + s + kk * 8] = f2bf(r2v[kk] * ps3);
    if (s == 0) xno[row] = fmaxf((nr2 > MAXN) ? MAXN : nr2, 1e-15f);
}

// ---------------------------------------------------------------- gram ------
// grid (16, 3, 8), block 256. mat: 0->G1(nv1,nv1) 1->G2(nv2,nv2) 2->M(nv1,nv2)
__global__ __launch_bounds__(256) void gram_kernel(const unsigned short* __restrict__ nv1b,
                                                   const unsigned short* __restrict__ nv2b,
                                                   float* __restrict__ G) {
    __shared__ float Ab[64 * 33], Bb[64 * 33];
    const int tile = blockIdx.x, mat = blockIdx.y, kc = blockIdx.z;
    const int ta = (tile & 3) * 32, tb = (tile >> 2) * 32;
    const unsigned short* Am = (mat == 1) ? nv2b : nv1b;
    const unsigned short* Bm = (mat == 0) ? nv1b : nv2b;
    const int tid = threadIdx.x;
    const int oa = tid & 31, obb = (tid >> 5) * 4;
    float acc[4] = {0.f, 0.f, 0.f, 0.f};
    for (int sc = 0; sc < 16; ++sc) {
        const int r0 = kc * 1024 + sc * 64;
        for (int i0 = tid; i0 < 2048; i0 += 256) {
            int rr = i0 >> 5, cc = i0 & 31;
            Ab[rr * 33 + cc] = bf2f(Am[(r0 + rr) * 128 + ta + cc]);
            Bb[rr * 33 + cc] = bf2f(Bm[(r0 + rr) * 128 + tb + cc]);
        }
        __syncthreads();
#pragma unroll 4
        for (int rr = 0; rr < 64; ++rr) {
            float av = Ab[rr * 33 + oa];
#pragma unroll
            for (int i = 0; i < 4; ++i) acc[i] += av * Bb[rr * 33 + obb + i];
        }
        __syncthreads();
    }
#pragma unroll
    for (int i = 0; i < 4; ++i)
        atomicAdd(&G[mat * 16384 + (ta + oa) * 128 + tb + obb + i], acc[i]);
}

// ---------------------------------------------------------------- rowcoef ---
// grid 256, block 256: 32 rows/block. R=v2'G1v2, C=v1'G2v1, X=v2'Mv1 -> P,Q
__global__ __launch_bounds__(256) void rowcoef_kernel(
    const float* __restrict__ G, const float* __restrict__ xn1, const float* __restrict__ xn2,
    const unsigned short* __restrict__ nv1b, const unsigned short* __restrict__ nv2b,
    float* __restrict__ P, float* __restrict__ Q) {
    __shared__ __align__(16) float v1L[32 * 132];
    __shared__ __align__(16) float v2L[32 * 132];
    __shared__ float tL[32 * 132];
    __shared__ float RCX[3][32];
    const int tid = threadIdx.x;
    const int rblk = blockIdx.x * 32;
    for (int i = tid; i < 4096; i += 256) {
        int r = i >> 7, c = i & 127;
        v1L[r * 132 + c] = bf2f(nv1b[(rblk + r) * 128 + c]);
        v2L[r * 132 + c] = bf2f(nv2b[(rblk + r) * 128 + c]);
    }
    __syncthreads();
    const int o = tid & 127, rb = tid >> 7;
    const int rA = tid >> 3, sA = tid & 7;
    for (int mat = 0; mat < 3; ++mat) {
        const float* vR = (mat == 0) ? v2L : v1L;      // w = G * vR
        const float* vL = (mat == 1) ? v1L : v2L;      // form = <vL, w>
        const float* Gm = G + mat * 16384;
        float tv[16];
#pragma unroll
        for (int rr = 0; rr < 16; ++rr) tv[rr] = 0.f;
        for (int k4 = 0; k4 < 128; k4 += 4) {
            const float4 gv = *reinterpret_cast<const float4*>(&Gm[o * 128 + k4]);
#pragma unroll
            for (int rr = 0; rr < 16; ++rr) {
                const float4 uv = *reinterpret_cast<const float4*>(&vR[(rb + rr * 2) * 132 + k4]);
                tv[rr] += uv.x * gv.x + uv.y * gv.y + uv.z * gv.z + uv.w * gv.w;
            }
        }
        __syncthreads();  // previous-mat tL consumers done
#pragma unroll
        for (int rr = 0; rr < 16; ++rr) {
            int rw = rb + rr * 2;
            tL[rw * 132 + o] = vL[rw * 132 + o] * tv[rr];
        }
        __syncthreads();
        float p = 0.f;
#pragma unroll
        for (int kk = 0; kk < 16; ++kk) p += tL[rA * 132 + sA + kk * 8];
        p = red8(p);
        if (sA == 0) RCX[mat][rA] = p;
    }
    __syncthreads();
    if (tid < 32) {
        const int row = rblk + tid;
        const float R = RCX[0][tid], Cc = RCX[1][tid], X = RCX[2][tid];
        const float xn1v = xn1[row], xn2v = xn2[row];
        const float mxn1 = fmaxf(sqrtf(fmaxf(R, 0.f)), 1e-15f);
        const float t1 = tanhf(mxn1 / xn2v * artanh_clip(xn2v));
        const float f1 = t1 / mxn1;
        const float mxn2 = fmaxf(sqrtf(fmaxf(Cc, 0.f)), 1e-15f);
        const float t2 = tanhf(mxn2 / xn1v * artanh_clip(xn1v));
        const float f2 = t2 / mxn2;
        const float x2 = f1 * f1 * R, y2 = f2 * f2 * Cc;
        const float xy = -f1 * f2 * X;
        const float rden = 1.f / fmaxf(1.f + 2.f * xy + x2 * y2, 1e-15f);
        P[row] = (1.f + 2.f * xy + y2) * f1 * rden;
        Q[row] = -(1.f - x2) * f2 * rden;
    }
}

// ---------------------------------------------------------------- fused -----
// grid 1024, block 512 (8 waves). XCD-aware decode: xcd=b&7 owns j-quarter
// js=xcd>>1 and 128 iblk slots -> per-XCD L2 working set ~2MB.
// Partials combined via atomicAdd into U(=d_out)/rs/qs (zeroed at launch).
__global__ __launch_bounds__(512, 2) void fused_kernel(
    const unsigned short* __restrict__ nv1b, const unsigned short* __restrict__ nv2b,
    const unsigned short* __restrict__ xtT,
    const float* __restrict__ P, const float* __restrict__ Q,
    float* __restrict__ U, float* __restrict__ rs, float* __restrict__ qs) {
    __shared__ float S1[32 * 132];                       // S[i, jblk + 0..127] (raw)
    __shared__ __align__(16) unsigned short adjb[32 * 136];
    __shared__ float PL[32], QL[32];
    __shared__ int s2flag;

    const int tid = threadIdx.x;
    const int w = tid >> 6, l = tid & 63;
    const int b = blockIdx.x;
    const int xcd = b & 7, slot = b >> 3;
    const int js = xcd >> 1;                      // 0..3: j-quarter
    const int iblk = ((xcd & 1) * 128 + slot) * 32;
    const int jb0 = js * 16;

    if (tid == 0) s2flag = 0;
    if (tid < 32) {
        PL[tid] = P[iblk + tid];
        QL[tid] = Q[iblk + tid];
    }
    __syncthreads();
    if (tid < 32 && fabsf(QL[tid]) > 1e-6f) atomicOr(&s2flag, 1);
    __syncthreads();
    const bool needS2 = (s2flag != 0);

    // persistent A fragments: nv2 rows iblk..iblk+31, full K=128
    short8 areg[2][4];
#pragma unroll
    for (int tr = 0; tr < 2; ++tr)
#pragma unroll
        for (int kk = 0; kk < 4; ++kk)
            areg[tr][kk] = *reinterpret_cast<const short8*>(
                &nv2b[(iblk + tr * 16 + (l & 15)) * 128 + kk * 32 + (l >> 4) * 8]);

    const f32x4 zero4 = {0.f, 0.f, 0.f, 0.f};
    f32x4 accU[2];
    accU[0] = zero4;
    accU[1] = zero4;
    float rsA[4] = {0.f, 0.f, 0.f, 0.f};
    float qA[4] = {0.f, 0.f, 0.f, 0.f};

    auto computeS1 = [&](int jb) {
        const int jblk = jb * 128;
        f32x4 acc0 = zero4, acc1 = zero4;
#pragma unroll
        for (int kk = 0; kk < 4; ++kk) {
            short8 bfr = *reinterpret_cast<const short8*>(
                &nv1b[(jblk + w * 16 + (l & 15)) * 128 + kk * 32 + (l >> 4) * 8]);
            acc0 = __builtin_amdgcn_mfma_f32_16x16x32_bf16(areg[0][kk], bfr, acc0, 0, 0, 0);
            acc1 = __builtin_amdgcn_mfma_f32_16x16x32_bf16(areg[1][kk], bfr, acc1, 0, 0, 0);
        }
#pragma unroll
        for (int v = 0; v < 4; ++v) {
            S1[((l >> 4) * 4 + v) * 132 + w * 16 + (l & 15)] = acc0[v];
            S1[(16 + (l >> 4) * 4 + v) * 132 + w * 16 + (l & 15)] = acc1[v];
        }
    };

    // rare exact path: S1[i][j] <- P_i*S1 + Q_i*(nv2_j . nv1_i), in place
    auto s2merge = [&](int jb) {
        const int jblk = jb * 128;
        f32x4 a20 = zero4, a21 = zero4;
#pragma unroll
        for (int kk = 0; kk < 4; ++kk) {
            short8 a2 = *reinterpret_cast<const short8*>(
                &nv2b[(jblk + w * 16 + (l & 15)) * 128 + kk * 32 + (l >> 4) * 8]);
            short8 b20 = *reinterpret_cast<const short8*>(
                &nv1b[(iblk + (l & 15)) * 128 + kk * 32 + (l >> 4) * 8]);
            short8 b21 = *reinterpret_cast<const short8*>(
                &nv1b[(iblk + 16 + (l & 15)) * 128 + kk * 32 + (l >> 4) * 8]);
            a20 = __builtin_amdgcn_mfma_f32_16x16x32_bf16(a2, b20, a20, 0, 0, 0);
            a21 = __builtin_amdgcn_mfma_f32_16x16x32_bf16(a2, b21, a21, 0, 0, 0);
        }
        const int jloc = w * 16 + (l >> 4) * 4;
        const int i0 = l & 15;
#pragma unroll
        for (int v = 0; v < 4; ++v) {
            S1[i0 * 132 + jloc + v] = PL[i0] * S1[i0 * 132 + jloc + v] + QL[i0] * a20[v];
            S1[(i0 + 16) * 132 + jloc + v] =
                PL[i0 + 16] * S1[(i0 + 16) * 132 + jloc + v] + QL[i0 + 16] * a21[v];
        }
    };

    computeS1(jb0);
    for (int jb = jb0; jb < jb0 + 16; ++jb) {
        const int jblk = jb * 128;
        __syncthreads();  // S1 ready; adjb free
        if (needS2) {
            s2merge(jb);
            __syncthreads();
        }
        // adj phase: rows w+8k, cols l and l+64. tanh(3a)=1-2/(exp2(8.656*a)+1)
        auto adjLoop = [&](bool dodiag) {
#pragma unroll
            for (int k = 0; k < 4; ++k) {
                const int r = w + 8 * k;
                const float Pv = PL[r];
#pragma unroll
                for (int h = 0; h < 2; ++h) {
                    const int c = l + 64 * h;
                    float sv = S1[r * 132 + c];
                    float a = needS2 ? sv : Pv * sv;
                    float e = __builtin_amdgcn_exp2f(a * 8.65617025f);
                    float t = 1.0f - 2.0f * __builtin_amdgcn_rcpf(e + 1.0f);
                    float ad = fmaxf(t, 0.0f);
                    if (dodiag && (iblk + r == jblk + c)) ad += 1e-4f;
                    rsA[k] += ad;
                    qA[k] += ad * ad;
                    adjb[r * 136 + c] = f2bf(ad);
                }
            }
        };
        if ((unsigned)(iblk - jblk) < 128u) adjLoop(true); else adjLoop(false);
        __syncthreads();  // adjb ready; S1 free
        // U += adjb[32][128] @ xt[jblk..][128cols]; wave w owns U cols w*16..+15
#pragma unroll
        for (int kk = 0; kk < 4; ++kk) {
            short8 bfr = *reinterpret_cast<const short8*>(
                &xtT[(w * 16 + (l & 15)) * 8192 + jblk + kk * 32 + (l >> 4) * 8]);
#pragma unroll
            for (int tr = 0; tr < 2; ++tr) {
                short8 a = *reinterpret_cast<const short8*>(
                    &adjb[(tr * 16 + (l & 15)) * 136 + kk * 32 + (l >> 4) * 8]);
                accU[tr] = __builtin_amdgcn_mfma_f32_16x16x32_bf16(a, bfr, accU[tr], 0, 0, 0);
            }
        }
        if (jb + 1 < jb0 + 16) computeS1(jb + 1);  // writes S1 post-bar2, read post-next-bar1
    }

    // combine partials (C layout: row=(l>>4)*4+v, col=l&15)
#pragma unroll
    for (int tr = 0; tr < 2; ++tr)
#pragma unroll
        for (int v = 0; v < 4; ++v)
            atomicAdd(&U[(iblk + tr * 16 + (l >> 4) * 4 + v) * 128 + w * 16 + (l & 15)],
                      accU[tr][v]);
#pragma unroll
    for (int k = 0; k < 4; ++k) {
        float rsv = red64(rsA[k]);
        float qv = red64(qA[k]);
        if (l == 0) {
            atomicAdd(&rs[iblk + w + 8 * k], rsv);
            atomicAdd(&qs[iblk + w + 8 * k], qv);
        }
    }
}

// ---------------------------------------------------------------- finalize --
// grid 2048, block 256: 4 rows/block, 64 lanes/row.
__global__ __launch_bounds__(256) void finalize_kernel(
    const float* __restrict__ U, const float* __restrict__ rs,
    const float* __restrict__ qs, float* __restrict__ out) {
    const int tid = threadIdx.x;
    const int row = blockIdx.x * 4 + (tid >> 6);
    const int l = tid & 63;
    const float u0 = U[row * 128 + l], u1 = U[row * 128 + 64 + l];
    const float rsv = rs[row];
    const float wv = (rsv == 0.f) ? 0.f : 1.f / rsv;
    const float m0 = u0 * wv, m1 = u1 * wv;
    const float mxn = fmaxf(sqrtf(red64(m0 * m0 + m1 * m1)), 1e-15f);
    const float xn = fmaxf(sqrtf(fmaxf(qs[row], 0.f)) * wv, 1e-15f);
    const float tt = tanhf(mxn / xn * artanh_clip(xn));
    const float nres = fmaxf(tt, 1e-15f);
    const float lsc = (tt / mxn) * (artanh_clip(nres) / nres);
    out[row * 128 + l] = m0 * lsc;
    out[row * 128 + 64 + l] = m1 * lsc;
}

// ---------------------------------------------------------------- launch ----
extern "C" void kernel_launch(void* const* d_in, const int* in_sizes, int n_in,
                              void* d_out, int out_size, void* d_ws, size_t ws_size,
                              hipStream_t stream) {
    const int* idx = (const int*)d_in[0];
    const float* x = (const float*)d_in[2];
    const float* emb1 = (const float*)d_in[3];
    const float* emb2 = (const float*)d_in[4];
    const float* W1 = (const float*)d_in[5];
    const float* b1 = (const float*)d_in[6];
    const float* W2 = (const float*)d_in[7];
    const float* b2 = (const float*)d_in[8];
    float* out = (float*)d_out;
    char* ws = (char*)d_ws;

    // ws footprint: 0x660000 = 6.6MB (proven ws_size >= ~8.7MB in R1/R2)
    unsigned short* nv1b = (unsigned short*)(ws + 0x000000);   // 2MB bf16 [8192][128]
    unsigned short* nv2b = (unsigned short*)(ws + 0x200000);   // 2MB
    unsigned short* xtT = (unsigned short*)(ws + 0x400000);    // 2MB bf16 [128][8192]
    float* G = (float*)(ws + 0x600000);                        // 3 x 128x128 fp32
    float* xn1 = (float*)(ws + 0x630000);
    float* xn2 = (float*)(ws + 0x638000);
    float* P = (float*)(ws + 0x640000);
    float* Q = (float*)(ws + 0x648000);
    float* rs = (float*)(ws + 0x650000);
    float* qs = (float*)(ws + 0x658000);
    float* U = out;  // U accumulated (atomics) directly in d_out; finalize in-place

    hipMemsetAsync(G, 0, 3 * 128 * 128 * sizeof(float), stream);
    hipMemsetAsync(rs, 0, 8192 * sizeof(float), stream);
    hipMemsetAsync(qs, 0, 8192 * sizeof(float), stream);
    hipMemsetAsync(U, 0, 8192 * 128 * sizeof(float), stream);
    prep_kernel<<<dim3(256, 3), 256, 0, stream>>>(idx, x, emb1, emb2, W1, W2, b1, b2,
                                                  nv1b, nv2b, xtT, xn1, xn2);
    gram_kernel<<<dim3(16, 3, 8), 256, 0, stream>>>(nv1b, nv2b, G);
    rowcoef_kernel<<<256, 256, 0, stream>>>(G, xn1, xn2, nv1b, nv2b, P, Q);
    fused_kernel<<<1024, 512, 0, stream>>>(nv1b, nv2b, xtT, P, Q, U, rs, qs);
    finalize_kernel<<<2048, 256, 0, stream>>>(U, rs, qs, out);
    (void)in_sizes; (void)n_in; (void)out_size; (void)ws_size; (void)d_in;
}